// Round 8
// baseline (763.946 us; speedup 1.0000x reference)
//
#include <hip/hip_runtime.h>
#include <math.h>

// KSIZE=3, STRIDE=1, RATE=2, FUSE_K=3, SCALE=10
#define CDIM 128
#define HF   128
#define WF   128
#define NP   4096   // 64*64 downsampled positions
#define NCHUNK 64   // softmax u-chunks (64 rows each)

// per-item workspace layout (floats):
//   bufD 16777216 | bufS 16777216 | s2 4096 | rnrm 4096 | mmp 4096 |
//   pm 262144 | ps 262144 | mcol 4096 | rscol 4096
#define ITEM_WS (2 * 16777216 + 3 * 4096 + 2 * (NCHUNK * NP) + 2 * 4096)

typedef __attribute__((ext_vector_type(8))) short short8;
typedef float __attribute__((ext_vector_type(4), aligned(16))) f4a16;
typedef float __attribute__((ext_vector_type(4), aligned(4)))  f4u;

__device__ inline ushort f2bf(float x) {
  union { float f; unsigned u; } v; v.f = x;
  unsigned r = v.u + 0x7fff + ((v.u >> 16) & 1);
  return (ushort)(r >> 16);
}
__device__ inline float bf2f(ushort h) {
  union { unsigned u; float f; } v; v.u = ((unsigned)h) << 16; return v.f;
}

__device__ inline void gl2lds16(const ushort* g, ushort* l) {
  __builtin_amdgcn_global_load_lds((const __attribute__((address_space(1))) void*)g,
                                   (__attribute__((address_space(3))) void*)l, 16, 0, 0);
}

// ---------------------------------------------------------------------------
__global__ __launch_bounds__(256) void k_prep(const float* __restrict__ f,
                                              const float* __restrict__ b,
                                              ushort* __restrict__ fcat,
                                              ushort* __restrict__ bcat,
                                              size_t zsF, size_t zsW) {
  size_t zW = (size_t)blockIdx.z * zsW;
  f += (size_t)blockIdx.z * zsF; b += (size_t)blockIdx.z * zsF;
  fcat += 2 * zW; bcat += 2 * zW;
  int idx = blockIdx.x * 256 + threadIdx.x;
  int c = idx & 127, pos = idx >> 7;
  int x = pos & 63, y = pos >> 6;
  int src = c * 16384 + y * 256 + x * 2;
  float fv = f[src], bv = b[src];
  ushort fh = f2bf(fv); ushort fl = f2bf(fv - bf2f(fh));
  ushort bh = f2bf(bv); ushort bl = f2bf(bv - bf2f(bh));
  size_t base = (size_t)pos * 384;
  fcat[base + c] = fh; fcat[base + 128 + c] = fl; fcat[base + 256 + c] = fh;
  bcat[base + c] = bh; bcat[base + 128 + c] = bh; bcat[base + 256 + c] = bl;
}

__global__ __launch_bounds__(256) void k_mmp(const float* __restrict__ mask,
                                             float* __restrict__ mmp,
                                             size_t zsM, size_t zsW) {
  mask += (size_t)blockIdx.z * zsM; mmp += (size_t)blockIdx.z * zsW;
  int a = blockIdx.x * 256 + threadIdx.x;
  int yb = a & 63, xb = a >> 6;
  float s = 0.f;
  for (int dy = -1; dy <= 1; ++dy)
    for (int dx = -1; dx <= 1; ++dx) {
      int y = yb + dy, x = xb + dx;
      if ((unsigned)y < 64u && (unsigned)x < 64u)
        s += mask[y * 256 + x * 2];
    }
  mmp[a] = (s == 0.0f) ? 1.0f : 0.0f;
}

__global__ __launch_bounds__(256) void k_sumsq(const float* __restrict__ b,
                                               float* __restrict__ s2,
                                               size_t zsF, size_t zsW) {
  b += (size_t)blockIdx.z * zsF; s2 += (size_t)blockIdx.z * zsW;
  int p = blockIdx.x * 256 + threadIdx.x;
  int x = p & 63, y = p >> 6;
  float s = 0.f;
  for (int c = 0; c < CDIM; ++c) {
    float v = b[c * 16384 + y * 256 + x * 2];
    s += v * v;
  }
  s2[p] = s;
}

__global__ __launch_bounds__(256) void k_norm(const float* __restrict__ s2,
                                              float* __restrict__ rnrm,
                                              size_t zsW) {
  s2 += (size_t)blockIdx.z * zsW; rnrm += (size_t)blockIdx.z * zsW;
  int p = blockIdx.x * 256 + threadIdx.x;
  int xb = p & 63, yb = p >> 6;
  float s = 0.f;
  for (int dy = -1; dy <= 1; ++dy)
    for (int dx = -1; dx <= 1; ++dx) {
      int y = yb + dy, x = xb + dx;
      if ((unsigned)y < 64u && (unsigned)x < 64u) s += s2[y * 64 + x];
    }
  rnrm[p] = rsqrtf(s + 1152.0f * 1.0e-4f);
}

// ---------------------------------------------------------------------------
// MFMA bf16 GEMM, 128x128 tile, 4 waves, BK=64, global_load_lds + global XOR swizzle.
__global__ __launch_bounds__(256) void k_mfma_gemm(const ushort* __restrict__ A,
                                                   const ushort* __restrict__ B,
                                                   float* __restrict__ Out,
                                                   int Kdim, int lda, int ldb, int ldo,
                                                   size_t zsW) {
  size_t zW = (size_t)blockIdx.z * zsW;
  A += 2 * zW; B += 2 * zW; Out += zW;
  __shared__ ushort As[128 * 64];
  __shared__ ushort Bs[128 * 64];
  int tid = threadIdx.x;
  int wave = tid >> 6, lane = tid & 63;
  int quad = lane >> 4, l16 = lane & 15;
  int m0 = blockIdx.y * 128, n0 = blockIdx.x * 128;
  int wm = (wave >> 1) * 64, wn = (wave & 1) * 64;
  int srow = lane >> 3;
  int g = lane & 7;
  int gperm = (g ^ srow) * 8;

  f4a16 acc[4][4];
#pragma unroll
  for (int i = 0; i < 4; ++i)
#pragma unroll
    for (int j = 0; j < 4; ++j) acc[i][j] = (f4a16){0.f, 0.f, 0.f, 0.f};

  for (int k0 = 0; k0 < Kdim; k0 += 64) {
#pragma unroll
    for (int i = 0; i < 4; ++i) {
      int rbase = wave * 32 + i * 8;
      gl2lds16(A + (size_t)(m0 + rbase + srow) * lda + k0 + gperm, &As[rbase * 64]);
      gl2lds16(B + (size_t)(n0 + rbase + srow) * ldb + k0 + gperm, &Bs[rbase * 64]);
    }
    __syncthreads();
#pragma unroll
    for (int s = 0; s < 2; ++s) {
      short8 afrag[4], bfrag[4];
#pragma unroll
      for (int t = 0; t < 4; ++t) {
        int am = wm + t * 16 + l16;
        int ga = ((s * 4 + quad) ^ (am & 7)) * 8;
        afrag[t] = *reinterpret_cast<const short8*>(&As[am * 64 + ga]);
        int bn = wn + t * 16 + l16;
        int gb = ((s * 4 + quad) ^ (bn & 7)) * 8;
        bfrag[t] = *reinterpret_cast<const short8*>(&Bs[bn * 64 + gb]);
      }
#pragma unroll
      for (int i = 0; i < 4; ++i)
#pragma unroll
        for (int j = 0; j < 4; ++j)
          acc[i][j] = __builtin_amdgcn_mfma_f32_16x16x32_bf16(afrag[i], bfrag[j], acc[i][j], 0, 0, 0);
    }
    __syncthreads();
  }
#pragma unroll
  for (int i = 0; i < 4; ++i)
#pragma unroll
    for (int j = 0; j < 4; ++j)
#pragma unroll
      for (int r = 0; r < 4; ++r)
        Out[(size_t)(m0 + wm + i * 16 + quad * 4 + r) * ldo + (n0 + wn + j * 16 + l16)] = acc[i][j][r];
}

// ---------------------------------------------------------------------------
// S0[p,q] = (sum of 9 diag-shifted D taps) * rnrm[p]; see R7 notes on edges.
__global__ __launch_bounds__(256) void k_s0(const float* __restrict__ D,
                                            const float* __restrict__ rnrm,
                                            float* __restrict__ S0,
                                            size_t zsW) {
  size_t zW = (size_t)blockIdx.z * zsW;
  D += zW; rnrm += zW; S0 += zW;
  int p = blockIdx.x;
  int yb = p >> 6, xb = p & 63;
  float rp = rnrm[p];
  int t = threadIdx.x;
#pragma unroll
  for (int it = 0; it < 4; ++it) {
    int q = (it * 256 + t) << 2;
    int qy = q >> 6, qx = q & 63;
    f4a16 acc = (f4a16){0.f, 0.f, 0.f, 0.f};
#pragma unroll
    for (int dy = -1; dy <= 1; ++dy) {
      if ((unsigned)(yb + dy) >= 64u) continue;
      if ((unsigned)(qy + dy) >= 64u) continue;
#pragma unroll
      for (int dx = -1; dx <= 1; ++dx) {
        if ((unsigned)(xb + dx) >= 64u) continue;
        int delta = dy * 64 + dx;
        const float* base = D + (size_t)(p + delta) * 4096;
        f4u v;
        if (dx == -1 && qx == 0) {
          f4u r = *(const f4u*)(base + q + delta + 1);
          v = (f4u){0.f, r.x, r.y, r.z};
        } else {
          v = *(const f4u*)(base + q + delta);
          if (dx == 1 && qx == 60) v.w = 0.f;
        }
        acc += v;
      }
    }
    acc *= rp;
    *(f4a16*)(S0 + ((size_t)p << 12) + q) = acc;
  }
}

// fuse1: F1[i,j] = sum_d S0[i+d, j+d], written permuted: Yp[pi(i)][b]=F1[i][pi(b)]
__global__ __launch_bounds__(256) void k_fuse1(const float* __restrict__ S0,
                                               float* __restrict__ Yp,
                                               size_t zsW) {
  size_t zW = (size_t)blockIdx.z * zsW;
  S0 += zW; Yp += zW;
  __shared__ float row[4160];
  int i = blockIdx.x;
  int t = threadIdx.x;
  const float* r0 = S0 + (size_t)(i - 1) * 4096;
  const float* r1 = S0 + (size_t)i * 4096;
  const float* r2 = S0 + (size_t)(i + 1) * 4096;
  bool up = (i > 0), dn = (i < 4095);
#pragma unroll
  for (int jj = 0; jj < 4; ++jj) {
    int j = (jj * 256 + t) << 2;
    f4u s = *(const f4u*)(r1 + j);
    if (up) {
      f4u a;
      if (j == 0) { f4u r = *(const f4u*)r0; a = (f4u){0.f, r.x, r.y, r.z}; }
      else a = *(const f4u*)(r0 + j - 1);
      s += a;
    }
    if (dn) {
      f4u d = *(const f4u*)(r2 + j + 1);
      if (j == 4092) d.w = 0.f;
      s += d;
    }
    int base = j + (j >> 6);
    row[base + 0] = s.x; row[base + 1] = s.y; row[base + 2] = s.z; row[base + 3] = s.w;
  }
  __syncthreads();
  int a = ((i & 63) << 6) | (i >> 6);
  float* orow = Yp + ((size_t)a << 12);
#pragma unroll
  for (int bb = 0; bb < 16; ++bb) {
    int b = bb * 256 + t;
    int jT = ((b & 63) << 6) | (b >> 6);
    orow[b] = row[jT + (jT >> 6)];
  }
}

// softmax partials over u of logits x = 10 * mmp[u] * diag3(Yp)[u,v]
__global__ __launch_bounds__(256) void k_smax_part(const float* __restrict__ Yp,
                                                   const float* __restrict__ mmp,
                                                   float* __restrict__ pm,
                                                   float* __restrict__ ps,
                                                   size_t zsW) {
  size_t zW = (size_t)blockIdx.z * zsW;
  Yp += zW; mmp += zW; pm += zW; ps += zW;
  int v = (blockIdx.x * 256 + threadIdx.x) << 2;
  int chunk = blockIdx.y;
  f4a16 m = (f4a16){-1e30f, -1e30f, -1e30f, -1e30f};
  f4a16 s = (f4a16){0.f, 0.f, 0.f, 0.f};
  int u0 = chunk * (4096 / NCHUNK);
  for (int u = u0; u < u0 + (4096 / NCHUNK); ++u) {
    const float* row = Yp + ((size_t)u << 12);
    f4u tv = *(const f4u*)(row + v);
    if (u > 0) {
      f4u a;
      if (v == 0) { f4u r = *(const f4u*)(row - 4096); a = (f4u){0.f, r.x, r.y, r.z}; }
      else a = *(const f4u*)(row - 4096 + v - 1);
      tv += a;
    }
    if (u < 4095) {
      f4u d = *(const f4u*)(row + 4096 + v + 1);
      if (v == 4092) d.w = 0.f;
      tv += d;
    }
    float g = 10.0f * mmp[u];
    f4u x = tv * g;
#pragma unroll
    for (int l = 0; l < 4; ++l) {
      float xl = x[l];
      if (xl > m[l]) { s[l] = s[l] * __expf(m[l] - xl) + 1.0f; m[l] = xl; }
      else           { s[l] += __expf(xl - m[l]); }
    }
  }
  *(f4a16*)(pm + chunk * NP + v) = m;
  *(f4a16*)(ps + chunk * NP + v) = s;
}

__global__ __launch_bounds__(256) void k_smax_red(const float* __restrict__ pm,
                                                  const float* __restrict__ ps,
                                                  float* __restrict__ mcol,
                                                  float* __restrict__ rscol,
                                                  size_t zsW) {
  size_t zW = (size_t)blockIdx.z * zsW;
  pm += zW; ps += zW; mcol += zW; rscol += zW;
  int v = (blockIdx.x * 256 + threadIdx.x) << 2;
  f4a16 m = *(const f4a16*)(pm + v);
  f4a16 s = *(const f4a16*)(ps + v);
  for (int ch = 1; ch < NCHUNK; ++ch) {
    f4a16 m2 = *(const f4a16*)(pm + ch * NP + v);
    f4a16 s2 = *(const f4a16*)(ps + ch * NP + v);
#pragma unroll
    for (int l = 0; l < 4; ++l) {
      if (m2[l] > m[l]) { s[l] = s[l] * __expf(m[l] - m2[l]) + s2[l]; m[l] = m2[l]; }
      else              { s[l] += s2[l] * __expf(m2[l] - m[l]); }
    }
  }
  *(f4a16*)(mcol + v) = m;
  f4a16 r;
#pragma unroll
  for (int l = 0; l < 4; ++l) r[l] = 1.0f / s[l];
  *(f4a16*)(rscol + v) = r;
}

// attnT: AT[q=pi(b)][a] = bf16( mmp[a]*exp(x - mcol[b])*rscol[b] )
__global__ __launch_bounds__(256) void k_attnT(const float* __restrict__ Yp,
                                               const float* __restrict__ mcol,
                                               const float* __restrict__ rscol,
                                               const float* __restrict__ mmp,
                                               ushort* __restrict__ AT,
                                               size_t zsW) {
  size_t zW = (size_t)blockIdx.z * zsW;
  Yp += zW; mcol += zW; rscol += zW; mmp += zW; AT += 2 * zW;
  __shared__ float T[64][65];
  int a0 = blockIdx.x * 64, b0 = blockIdx.y * 64;
  int t = threadIdx.x;
  int i = t >> 4, j4 = (t & 15) << 2;
#pragma unroll
  for (int r = 0; r < 4; ++r) {
    int al = r * 16 + i;
    int a = a0 + al;
    const float* row = Yp + ((size_t)a << 12);
    int b = b0 + j4;
    f4u y = *(const f4u*)(row + b);
    if (a > 0) {
      f4u u_;
      if (b == 0) { f4u rr = *(const f4u*)(row - 4096); u_ = (f4u){0.f, rr.x, rr.y, rr.z}; }
      else u_ = *(const f4u*)(row - 4096 + b - 1);
      y += u_;
    }
    if (a < 4095) {
      f4u d = *(const f4u*)(row + 4096 + b + 1);
      if (b == 4092) d.w = 0.f;
      y += d;
    }
    float g = mmp[a];
    f4a16 mc = *(const f4a16*)(mcol + b);
    f4a16 rs = *(const f4a16*)(rscol + b);
    f4u x = y * (10.0f * g);
#pragma unroll
    for (int l = 0; l < 4; ++l)
      T[al][j4 + l] = g * __expf(x[l] - mc[l]) * rs[l];
  }
  __syncthreads();
  int by0 = b0 >> 6;
  int c2 = (t & 31) << 1;
  int blb = t >> 5;
#pragma unroll
  for (int r = 0; r < 8; ++r) {
    int bl = r * 8 + blb;
    int q = bl * 64 + by0;
    unsigned lo = (unsigned)f2bf(T[c2][bl]);
    unsigned hi = (unsigned)f2bf(T[c2 + 1][bl]);
    *(unsigned*)(AT + ((size_t)q << 12) + a0 + c2) = lo | (hi << 16);
  }
}

// VtT'[k2][a] = bf16(Vt[k2][pi(a)])
__global__ __launch_bounds__(256) void k_vtT(const float* __restrict__ b,
                                             ushort* __restrict__ VtT,
                                             size_t zsF, size_t zsW) {
  b += (size_t)blockIdx.z * zsF; VtT += 2 * (size_t)blockIdx.z * zsW;
  __shared__ float T[64][65];
  int k2 = blockIdx.x;
  int t = threadIdx.x;
  int c = k2 >> 4, dy = (k2 >> 2) & 3, dx = k2 & 3;
  int px = t & 63;
#pragma unroll
  for (int r = 0; r < 16; ++r) {
    int py = r * 4 + (t >> 6);
    int sy = 2 * py + dy - 1, sx = 2 * px + dx - 1;
    float v = 0.f;
    if ((unsigned)sy < (unsigned)HF && (unsigned)sx < (unsigned)WF)
      v = b[c * 16384 + sy * 128 + sx];
    T[py][px] = v;
  }
  __syncthreads();
  ushort* orow = VtT + (size_t)k2 * 4096;
#pragma unroll
  for (int r = 0; r < 16; ++r) {
    int a = r * 256 + t;
    orow[a] = f2bf(T[a & 63][a >> 6]);
  }
}

// scatter M[(c,dy,dx), q] -> out, /4
__global__ __launch_bounds__(256) void k_scatter(const float* __restrict__ M,
                                                 float* __restrict__ out,
                                                 size_t zsW, size_t zsF) {
  M += (size_t)blockIdx.z * zsW; out += (size_t)blockIdx.z * zsF;
  int idx = blockIdx.x * 256 + threadIdx.x;
  int ox = idx & 127, oy = (idx >> 7) & 127, c = idx >> 14;
  int qy[2], dyv[2], qx[2], dxv[2];
  if (oy & 1) { qy[0] = (oy - 1) >> 1; dyv[0] = 2; qy[1] = (oy + 1) >> 1; dyv[1] = 0; }
  else        { qy[0] = (oy >> 1) - 1; dyv[0] = 3; qy[1] = oy >> 1;       dyv[1] = 1; }
  if (ox & 1) { qx[0] = (ox - 1) >> 1; dxv[0] = 2; qx[1] = (ox + 1) >> 1; dxv[1] = 0; }
  else        { qx[0] = (ox >> 1) - 1; dxv[0] = 3; qx[1] = ox >> 1;       dxv[1] = 1; }
  float s = 0.f;
#pragma unroll
  for (int i = 0; i < 2; ++i) {
    if ((unsigned)qy[i] >= 64u) continue;
#pragma unroll
    for (int j = 0; j < 2; ++j) {
      if ((unsigned)qx[j] >= 64u) continue;
      int k = c * 16 + dyv[i] * 4 + dxv[j];
      s += M[(size_t)k * NP + qy[i] * 64 + qx[j]];
    }
  }
  out[idx] = 0.25f * s;
}

// ---------------------------------------------------------------------------
static void run_pipeline(const float* f, const float* b, const float* mk, float* out,
                         float* ws, int nz, size_t zsF, size_t zsM, size_t zsW,
                         hipStream_t stream) {
  float* bufD = ws;                          // 64MB: D -> Yp -> M
  float* bufS = ws + 16777216;               // 64MB: {fcat,bcat} -> S0 -> {AT, VtT}
  ushort* fcat = (ushort*)bufS;
  ushort* bcat = (ushort*)(bufS + 786432);
  float* S0  = bufS;
  float* Yp  = bufD;
  ushort* AT  = (ushort*)bufS;
  ushort* VtT = (ushort*)(bufS + 8388608);
  float* Mbuf = bufD;
  float* smalls = ws + 2 * 16777216;
  float* s2    = smalls;
  float* rnrm  = s2 + 4096;
  float* mmp   = rnrm + 4096;
  float* pm    = mmp + 4096;
  float* ps    = pm + NCHUNK * NP;
  float* mcol  = ps + NCHUNK * NP;
  float* rscol = mcol + 4096;

  k_prep<<<dim3(2048, 1, nz), 256, 0, stream>>>(f, b, fcat, bcat, zsF, zsW);
  k_mmp<<<dim3(16, 1, nz), 256, 0, stream>>>(mk, mmp, zsM, zsW);
  k_sumsq<<<dim3(16, 1, nz), 256, 0, stream>>>(b, s2, zsF, zsW);
  k_norm<<<dim3(16, 1, nz), 256, 0, stream>>>(s2, rnrm, zsW);
  k_mfma_gemm<<<dim3(32, 32, nz), 256, 0, stream>>>(bcat, fcat, bufD, 384, 384, 384, NP, zsW);
  k_s0<<<dim3(4096, 1, nz), 256, 0, stream>>>(bufD, rnrm, S0, zsW);
  k_fuse1<<<dim3(4096, 1, nz), 256, 0, stream>>>(S0, Yp, zsW);
  k_smax_part<<<dim3(4, NCHUNK, nz), 256, 0, stream>>>(Yp, mmp, pm, ps, zsW);
  k_smax_red<<<dim3(4, 1, nz), 256, 0, stream>>>(pm, ps, mcol, rscol, zsW);
  k_attnT<<<dim3(64, 64, nz), 256, 0, stream>>>(Yp, mcol, rscol, mmp, AT, zsW);
  k_vtT<<<dim3(2048, 1, nz), 256, 0, stream>>>(b, VtT, zsF, zsW);
  k_mfma_gemm<<<dim3(32, 16, nz), 256, 0, stream>>>(VtT, AT, Mbuf, NP, NP, NP, NP, zsW);
  k_scatter<<<dim3(8192, 1, nz), 256, 0, stream>>>(Mbuf, out, zsW, zsF);
}

extern "C" void kernel_launch(void* const* d_in, const int* in_sizes, int n_in,
                              void* d_out, int out_size, void* d_ws, size_t ws_size,
                              hipStream_t stream) {
  const float* f_all = (const float*)d_in[0];
  const float* b_all = (const float*)d_in[1];
  const float* m_all = (const float*)d_in[2];
  float* out = (float*)d_out;
  float* ws = (float*)d_ws;

  const size_t zsF = (size_t)CDIM * HF * WF;   // 2097152
  const size_t zsM = (size_t)HF * WF;          // 16384

  if (ws_size >= (size_t)2 * ITEM_WS * sizeof(float)) {
    // batched: both items in one set of dispatches (grid.z = 2)
    run_pipeline(f_all, b_all, m_all, out, ws, 2, zsF, zsM, (size_t)ITEM_WS, stream);
  } else {
    // sequential fallback (R7 behavior)
    for (int it = 0; it < 2; ++it) {
      run_pipeline(f_all + it * zsF, b_all + it * zsF, m_all + it * zsM,
                   out + it * zsF, ws, 1, 0, 0, 0, stream);
    }
  }
}

// Round 9
// 752.383 us; speedup vs baseline: 1.0154x; 1.0154x over previous
//
#include <hip/hip_runtime.h>
#include <math.h>

// KSIZE=3, STRIDE=1, RATE=2, FUSE_K=3, SCALE=10
#define CDIM 128
#define HF   128
#define WF   128
#define NP   4096   // 64*64 downsampled positions
#define NCHUNK 64   // softmax u-chunks (64 rows each)

typedef __attribute__((ext_vector_type(8))) short short8;
typedef float __attribute__((ext_vector_type(4), aligned(16))) f4a16;
typedef float __attribute__((ext_vector_type(4), aligned(4)))  f4u;

__device__ inline ushort f2bf(float x) {
  union { float f; unsigned u; } v; v.f = x;
  unsigned r = v.u + 0x7fff + ((v.u >> 16) & 1);
  return (ushort)(r >> 16);
}
__device__ inline float bf2f(ushort h) {
  union { unsigned u; float f; } v; v.u = ((unsigned)h) << 16; return v.f;
}

__device__ inline void gl2lds16(const ushort* g, ushort* l) {
  __builtin_amdgcn_global_load_lds((const __attribute__((address_space(1))) void*)g,
                                   (__attribute__((address_space(3))) void*)l, 16, 0, 0);
}

// ---------------------------------------------------------------------------
// prep: downsample + split fp32 -> (hi,lo) bf16 K-major cat operands, AND
// s2[p] = sum_c b_ds[c,p]^2 (wave-uniform pos -> shuffle reduce, LDS combine).
//   bcat[pos][0:128]=b_hi [128:256]=b_hi [256:384]=b_lo
//   fcat[pos][0:128]=f_hi [128:256]=f_lo [256:384]=f_hi
__global__ __launch_bounds__(256) void k_prep(const float* __restrict__ f,
                                              const float* __restrict__ b,
                                              ushort* __restrict__ fcat,
                                              ushort* __restrict__ bcat,
                                              float* __restrict__ s2) {
  int idx = blockIdx.x * 256 + threadIdx.x;   // 524288
  int c = idx & 127, pos = idx >> 7;
  int x = pos & 63, y = pos >> 6;
  int src = c * 16384 + y * 256 + x * 2;
  float fv = f[src], bv = b[src];
  ushort fh = f2bf(fv); ushort fl = f2bf(fv - bf2f(fh));
  ushort bh = f2bf(bv); ushort bl = f2bf(bv - bf2f(bh));
  size_t base = (size_t)pos * 384;
  fcat[base + c] = fh; fcat[base + 128 + c] = fl; fcat[base + 256 + c] = fh;
  bcat[base + c] = bh; bcat[base + 128 + c] = bh; bcat[base + 256 + c] = bl;
  // s2: block covers pos {2*bx, 2*bx+1}; waves 0,1 -> pos0, waves 2,3 -> pos1
  float sq = bv * bv;
#pragma unroll
  for (int off = 32; off; off >>= 1) sq += __shfl_down(sq, off);
  __shared__ float wsum[4];
  if ((threadIdx.x & 63) == 0) wsum[threadIdx.x >> 6] = sq;
  __syncthreads();
  if (threadIdx.x == 0) s2[blockIdx.x * 2]     = wsum[0] + wsum[1];
  if (threadIdx.x == 1) s2[blockIdx.x * 2 + 1] = wsum[2] + wsum[3];
}

// merged: blocks 0..15 -> mmp[a] (mask gate at p=pi(a)); 16..31 -> rnrm[p]
__global__ __launch_bounds__(256) void k_mmpnorm(const float* __restrict__ mask,
                                                 const float* __restrict__ s2,
                                                 float* __restrict__ mmp,
                                                 float* __restrict__ rnrm) {
  int bx = blockIdx.x, t = threadIdx.x;
  if (bx < 16) {
    int a = bx * 256 + t;
    int yb = a & 63, xb = a >> 6;               // p = pi(a)
    float s = 0.f;
    for (int dy = -1; dy <= 1; ++dy)
      for (int dx = -1; dx <= 1; ++dx) {
        int y = yb + dy, x = xb + dx;
        if ((unsigned)y < 64u && (unsigned)x < 64u)
          s += mask[y * 256 + x * 2];
      }
    mmp[a] = (s == 0.0f) ? 1.0f : 0.0f;
  } else {
    int p = (bx - 16) * 256 + t;
    int xb = p & 63, yb = p >> 6;
    float s = 0.f;
    for (int dy = -1; dy <= 1; ++dy)
      for (int dx = -1; dx <= 1; ++dx) {
        int y = yb + dy, x = xb + dx;
        if ((unsigned)y < 64u && (unsigned)x < 64u) s += s2[y * 64 + x];
      }
    rnrm[p] = rsqrtf(s + 1152.0f * 1.0e-4f);
  }
}

// ---------------------------------------------------------------------------
// MFMA bf16 GEMM, 128x128 tile, 4 waves, BK=64, global_load_lds + global XOR
// swizzle. blockIdx.z = K-split: operands offset by z*kz (elements along K),
// output offset by z*oz (partial-sum buffer).
__global__ __launch_bounds__(256) void k_mfma_gemm(const ushort* __restrict__ A,
                                                   const ushort* __restrict__ B,
                                                   float* __restrict__ Out,
                                                   int Kdim, int lda, int ldb, int ldo,
                                                   size_t kz, size_t oz) {
  A += (size_t)blockIdx.z * kz; B += (size_t)blockIdx.z * kz;
  Out += (size_t)blockIdx.z * oz;
  __shared__ ushort As[128 * 64];
  __shared__ ushort Bs[128 * 64];
  int tid = threadIdx.x;
  int wave = tid >> 6, lane = tid & 63;
  int quad = lane >> 4, l16 = lane & 15;
  int m0 = blockIdx.y * 128, n0 = blockIdx.x * 128;
  int wm = (wave >> 1) * 64, wn = (wave & 1) * 64;
  int srow = lane >> 3;
  int g = lane & 7;
  int gperm = (g ^ srow) * 8;

  f4a16 acc[4][4];
#pragma unroll
  for (int i = 0; i < 4; ++i)
#pragma unroll
    for (int j = 0; j < 4; ++j) acc[i][j] = (f4a16){0.f, 0.f, 0.f, 0.f};

  for (int k0 = 0; k0 < Kdim; k0 += 64) {
#pragma unroll
    for (int i = 0; i < 4; ++i) {
      int rbase = wave * 32 + i * 8;
      gl2lds16(A + (size_t)(m0 + rbase + srow) * lda + k0 + gperm, &As[rbase * 64]);
      gl2lds16(B + (size_t)(n0 + rbase + srow) * ldb + k0 + gperm, &Bs[rbase * 64]);
    }
    __syncthreads();
#pragma unroll
    for (int s = 0; s < 2; ++s) {
      short8 afrag[4], bfrag[4];
#pragma unroll
      for (int t = 0; t < 4; ++t) {
        int am = wm + t * 16 + l16;
        int ga = ((s * 4 + quad) ^ (am & 7)) * 8;
        afrag[t] = *reinterpret_cast<const short8*>(&As[am * 64 + ga]);
        int bn = wn + t * 16 + l16;
        int gb = ((s * 4 + quad) ^ (bn & 7)) * 8;
        bfrag[t] = *reinterpret_cast<const short8*>(&Bs[bn * 64 + gb]);
      }
#pragma unroll
      for (int i = 0; i < 4; ++i)
#pragma unroll
        for (int j = 0; j < 4; ++j)
          acc[i][j] = __builtin_amdgcn_mfma_f32_16x16x32_bf16(afrag[i], bfrag[j], acc[i][j], 0, 0, 0);
    }
    __syncthreads();
  }
#pragma unroll
  for (int i = 0; i < 4; ++i)
#pragma unroll
    for (int j = 0; j < 4; ++j)
#pragma unroll
      for (int r = 0; r < 4; ++r)
        Out[(size_t)(m0 + wm + i * 16 + quad * 4 + r) * ldo + (n0 + wn + j * 16 + l16)] = acc[i][j][r];
}

// ---------------------------------------------------------------------------
// S0[p,q] = (sum of 9 diag-shifted D taps) * rnrm[p]
__global__ __launch_bounds__(256) void k_s0(const float* __restrict__ D,
                                            const float* __restrict__ rnrm,
                                            float* __restrict__ S0) {
  int p = blockIdx.x;
  int yb = p >> 6, xb = p & 63;
  float rp = rnrm[p];
  int t = threadIdx.x;
#pragma unroll
  for (int it = 0; it < 4; ++it) {
    int q = (it * 256 + t) << 2;
    int qy = q >> 6, qx = q & 63;
    f4a16 acc = (f4a16){0.f, 0.f, 0.f, 0.f};
#pragma unroll
    for (int dy = -1; dy <= 1; ++dy) {
      if ((unsigned)(yb + dy) >= 64u) continue;
      if ((unsigned)(qy + dy) >= 64u) continue;
#pragma unroll
      for (int dx = -1; dx <= 1; ++dx) {
        if ((unsigned)(xb + dx) >= 64u) continue;
        int delta = dy * 64 + dx;
        const float* base = D + (size_t)(p + delta) * 4096;
        f4u v;
        if (dx == -1 && qx == 0) {
          f4u r = *(const f4u*)(base + q + delta + 1);  // avoid negative addr
          v = (f4u){0.f, r.x, r.y, r.z};
        } else {
          v = *(const f4u*)(base + q + delta);
          if (dx == 1 && qx == 60) v.w = 0.f;
        }
        acc += v;
      }
    }
    acc *= rp;
    *(f4a16*)(S0 + ((size_t)p << 12) + q) = acc;
  }
}

// fuse1: F1[i,j] = sum_d S0[i+d, j+d], written permuted: Yp[pi(i)][b]=F1[i][pi(b)]
__global__ __launch_bounds__(256) void k_fuse1(const float* __restrict__ S0,
                                               float* __restrict__ Yp) {
  __shared__ float row[4160];
  int i = blockIdx.x;
  int t = threadIdx.x;
  const float* r0 = S0 + (size_t)(i - 1) * 4096;
  const float* r1 = S0 + (size_t)i * 4096;
  const float* r2 = S0 + (size_t)(i + 1) * 4096;
  bool up = (i > 0), dn = (i < 4095);
#pragma unroll
  for (int jj = 0; jj < 4; ++jj) {
    int j = (jj * 256 + t) << 2;
    f4u s = *(const f4u*)(r1 + j);
    if (up) {
      f4u a;
      if (j == 0) { f4u r = *(const f4u*)r0; a = (f4u){0.f, r.x, r.y, r.z}; }
      else a = *(const f4u*)(r0 + j - 1);
      s += a;
    }
    if (dn) {
      f4u d = *(const f4u*)(r2 + j + 1);
      if (j == 4092) d.w = 0.f;
      s += d;
    }
    int base = j + (j >> 6);
    row[base + 0] = s.x; row[base + 1] = s.y; row[base + 2] = s.z; row[base + 3] = s.w;
  }
  __syncthreads();
  int a = ((i & 63) << 6) | (i >> 6);
  float* orow = Yp + ((size_t)a << 12);
#pragma unroll
  for (int bb = 0; bb < 16; ++bb) {
    int b = bb * 256 + t;
    int jT = ((b & 63) << 6) | (b >> 6);
    orow[b] = row[jT + (jT >> 6)];
  }
}

// softmax partials over u of logits x = 10 * mmp[u] * diag3(Yp)[u,v]
__global__ __launch_bounds__(256) void k_smax_part(const float* __restrict__ Yp,
                                                   const float* __restrict__ mmp,
                                                   float* __restrict__ pm,
                                                   float* __restrict__ ps) {
  int v = (blockIdx.x * 256 + threadIdx.x) << 2;
  int chunk = blockIdx.y;
  f4a16 m = (f4a16){-1e30f, -1e30f, -1e30f, -1e30f};
  f4a16 s = (f4a16){0.f, 0.f, 0.f, 0.f};
  int u0 = chunk * (4096 / NCHUNK);
  for (int u = u0; u < u0 + (4096 / NCHUNK); ++u) {
    const float* row = Yp + ((size_t)u << 12);
    f4u tv = *(const f4u*)(row + v);
    if (u > 0) {
      f4u a;
      if (v == 0) { f4u r = *(const f4u*)(row - 4096); a = (f4u){0.f, r.x, r.y, r.z}; }
      else a = *(const f4u*)(row - 4096 + v - 1);
      tv += a;
    }
    if (u < 4095) {
      f4u d = *(const f4u*)(row + 4096 + v + 1);
      if (v == 4092) d.w = 0.f;
      tv += d;
    }
    float g = 10.0f * mmp[u];
    f4u x = tv * g;
#pragma unroll
    for (int l = 0; l < 4; ++l) {
      float xl = x[l];
      if (xl > m[l]) { s[l] = s[l] * __expf(m[l] - xl) + 1.0f; m[l] = xl; }
      else           { s[l] += __expf(xl - m[l]); }
    }
  }
  *(f4a16*)(pm + chunk * NP + v) = m;
  *(f4a16*)(ps + chunk * NP + v) = s;
}

__global__ __launch_bounds__(256) void k_smax_red(const float* __restrict__ pm,
                                                  const float* __restrict__ ps,
                                                  float* __restrict__ mcol,
                                                  float* __restrict__ rscol) {
  int v = (blockIdx.x * 256 + threadIdx.x) << 2;
  f4a16 m = *(const f4a16*)(pm + v);
  f4a16 s = *(const f4a16*)(ps + v);
  for (int ch = 1; ch < NCHUNK; ++ch) {
    f4a16 m2 = *(const f4a16*)(pm + ch * NP + v);
    f4a16 s2 = *(const f4a16*)(ps + ch * NP + v);
#pragma unroll
    for (int l = 0; l < 4; ++l) {
      if (m2[l] > m[l]) { s[l] = s[l] * __expf(m[l] - m2[l]) + s2[l]; m[l] = m2[l]; }
      else              { s[l] += s2[l] * __expf(m2[l] - m[l]); }
    }
  }
  *(f4a16*)(mcol + v) = m;
  f4a16 r;
#pragma unroll
  for (int l = 0; l < 4; ++l) r[l] = 1.0f / s[l];
  *(f4a16*)(rscol + v) = r;
}

// attnT: AT[q=pi(b)][a] = bf16( mmp[a]*exp(x - mcol[b])*rscol[b] )
__global__ __launch_bounds__(256) void k_attnT(const float* __restrict__ Yp,
                                               const float* __restrict__ mcol,
                                               const float* __restrict__ rscol,
                                               const float* __restrict__ mmp,
                                               ushort* __restrict__ AT) {
  __shared__ float T[64][65];
  int a0 = blockIdx.x * 64, b0 = blockIdx.y * 64;
  int t = threadIdx.x;
  int i = t >> 4, j4 = (t & 15) << 2;
#pragma unroll
  for (int r = 0; r < 4; ++r) {
    int al = r * 16 + i;
    int a = a0 + al;
    const float* row = Yp + ((size_t)a << 12);
    int b = b0 + j4;
    f4u y = *(const f4u*)(row + b);
    if (a > 0) {
      f4u u_;
      if (b == 0) { f4u rr = *(const f4u*)(row - 4096); u_ = (f4u){0.f, rr.x, rr.y, rr.z}; }
      else u_ = *(const f4u*)(row - 4096 + b - 1);
      y += u_;
    }
    if (a < 4095) {
      f4u d = *(const f4u*)(row + 4096 + b + 1);
      if (b == 4092) d.w = 0.f;
      y += d;
    }
    float g = mmp[a];
    f4a16 mc = *(const f4a16*)(mcol + b);
    f4a16 rs = *(const f4a16*)(rscol + b);
    f4u x = y * (10.0f * g);
#pragma unroll
    for (int l = 0; l < 4; ++l)
      T[al][j4 + l] = g * __expf(x[l] - mc[l]) * rs[l];
  }
  __syncthreads();
  int by0 = b0 >> 6;
  int c2 = (t & 31) << 1;
  int blb = t >> 5;
#pragma unroll
  for (int r = 0; r < 8; ++r) {
    int bl = r * 8 + blb;
    int q = bl * 64 + by0;
    unsigned lo = (unsigned)f2bf(T[c2][bl]);
    unsigned hi = (unsigned)f2bf(T[c2 + 1][bl]);
    *(unsigned*)(AT + ((size_t)q << 12) + a0 + c2) = lo | (hi << 16);
  }
}

// VtT'[k2][a] = bf16(Vt[k2][pi(a)])
__global__ __launch_bounds__(256) void k_vtT(const float* __restrict__ b,
                                             ushort* __restrict__ VtT) {
  __shared__ float T[64][65];
  int k2 = blockIdx.x;
  int t = threadIdx.x;
  int c = k2 >> 4, dy = (k2 >> 2) & 3, dx = k2 & 3;
  int px = t & 63;
#pragma unroll
  for (int r = 0; r < 16; ++r) {
    int py = r * 4 + (t >> 6);
    int sy = 2 * py + dy - 1, sx = 2 * px + dx - 1;
    float v = 0.f;
    if ((unsigned)sy < (unsigned)HF && (unsigned)sx < (unsigned)WF)
      v = b[c * 16384 + sy * 128 + sx];
    T[py][px] = v;
  }
  __syncthreads();
  ushort* orow = VtT + (size_t)k2 * 4096;
#pragma unroll
  for (int r = 0; r < 16; ++r) {
    int a = r * 256 + t;
    orow[a] = f2bf(T[a & 63][a >> 6]);
  }
}

// scatter: sums BOTH split-K partials M0,M1 then transposed-conv scatter, /4
__global__ __launch_bounds__(256) void k_scatter(const float* __restrict__ M,
                                                 float* __restrict__ out) {
  const float* M1 = M + 8388608;
  int idx = blockIdx.x * 256 + threadIdx.x;
  int ox = idx & 127, oy = (idx >> 7) & 127, c = idx >> 14;
  int qy[2], dyv[2], qx[2], dxv[2];
  if (oy & 1) { qy[0] = (oy - 1) >> 1; dyv[0] = 2; qy[1] = (oy + 1) >> 1; dyv[1] = 0; }
  else        { qy[0] = (oy >> 1) - 1; dyv[0] = 3; qy[1] = oy >> 1;       dyv[1] = 1; }
  if (ox & 1) { qx[0] = (ox - 1) >> 1; dxv[0] = 2; qx[1] = (ox + 1) >> 1; dxv[1] = 0; }
  else        { qx[0] = (ox >> 1) - 1; dxv[0] = 3; qx[1] = ox >> 1;       dxv[1] = 1; }
  float s = 0.f;
#pragma unroll
  for (int i = 0; i < 2; ++i) {
    if ((unsigned)qy[i] >= 64u) continue;
#pragma unroll
    for (int j = 0; j < 2; ++j) {
      if ((unsigned)qx[j] >= 64u) continue;
      size_t off = (size_t)(c * 16 + dyv[i] * 4 + dxv[j]) * NP + qy[i] * 64 + qx[j];
      s += M[off] + M1[off];
    }
  }
  out[idx] = 0.25f * s;
}

// ---------------------------------------------------------------------------
extern "C" void kernel_launch(void* const* d_in, const int* in_sizes, int n_in,
                              void* d_out, int out_size, void* d_ws, size_t ws_size,
                              hipStream_t stream) {
  const float* f_all = (const float*)d_in[0];
  const float* b_all = (const float*)d_in[1];
  const float* m_all = (const float*)d_in[2];
  float* out = (float*)d_out;

  float* ws = (float*)d_ws;
  float* bufD = ws;                          // 64MB: D -> Yp -> M(2 partials)
  float* bufS = ws + 16777216;               // 64MB: {fcat,bcat} -> S0 -> {AT, VtT}
  ushort* fcat = (ushort*)bufS;
  ushort* bcat = (ushort*)(bufS + 786432);
  float* S0  = bufS;
  float* Yp  = bufD;
  ushort* AT  = (ushort*)bufS;               // 32MB
  ushort* VtT = (ushort*)(bufS + 8388608);   // 16MB
  float* Mbuf = bufD;                        // 2 x 32MB partials (clobbers Yp)
  float* smalls = ws + 2 * 16777216;
  float* s2    = smalls;
  float* rnrm  = s2 + 4096;
  float* mmp   = rnrm + 4096;
  float* pm    = mmp + 4096;
  float* ps    = pm + NCHUNK * NP;
  float* mcol  = ps + NCHUNK * NP;
  float* rscol = mcol + 4096;

  const size_t zsF = (size_t)CDIM * HF * WF;
  const size_t zsM = (size_t)HF * WF;

  for (int it = 0; it < 2; ++it) {
    const float* f = f_all + it * zsF;
    const float* b = b_all + it * zsF;
    const float* mk = m_all + it * zsM;
    float* o = out + it * zsF;

    k_prep<<<2048, 256, 0, stream>>>(f, b, fcat, bcat, s2);
    k_mmpnorm<<<32, 256, 0, stream>>>(mk, s2, mmp, rnrm);
    // D[p,q] (fp32-accurate via split-bf16, K=384)
    k_mfma_gemm<<<dim3(32, 32, 1), 256, 0, stream>>>(bcat, fcat, bufD, 384, 384, 384, NP, 0, 0);
    k_s0<<<4096, 256, 0, stream>>>(bufD, rnrm, S0);
    k_fuse1<<<4096, 256, 0, stream>>>(S0, Yp);
    k_smax_part<<<dim3(4, NCHUNK), 256, 0, stream>>>(Yp, mmp, pm, ps);
    k_smax_red<<<4, 256, 0, stream>>>(pm, ps, mcol, rscol);
    k_attnT<<<dim3(64, 64), 256, 0, stream>>>(Yp, mcol, rscol, mmp, AT);
    k_vtT<<<2048, 256, 0, stream>>>(b, VtT);
    // M[k2,q] = sum_a VtT[k2,a] * AT[q,a], split-K=2 (z: K-half), partial sums
    k_mfma_gemm<<<dim3(32, 16, 2), 256, 0, stream>>>(VtT, AT, Mbuf, 2048, NP, NP, NP,
                                                     2048, 8388608);
    k_scatter<<<8192, 256, 0, stream>>>(Mbuf, o);
  }
}

// Round 10
// 678.205 us; speedup vs baseline: 1.1264x; 1.1094x over previous
//
#include <hip/hip_runtime.h>
#include <math.h>

// KSIZE=3, STRIDE=1, RATE=2, FUSE_K=3, SCALE=10
#define CDIM 128
#define HF   128
#define WF   128
#define NP   4096   // 64*64 downsampled positions
#define NCHUNK 64   // softmax u-chunks (64 rows each)

typedef __attribute__((ext_vector_type(8))) short short8;
typedef float __attribute__((ext_vector_type(4), aligned(16))) f4a16;
typedef float __attribute__((ext_vector_type(4), aligned(4)))  f4u;

__device__ inline ushort f2bf(float x) {
  union { float f; unsigned u; } v; v.f = x;
  unsigned r = v.u + 0x7fff + ((v.u >> 16) & 1);
  return (ushort)(r >> 16);
}
__device__ inline float bf2f(ushort h) {
  union { unsigned u; float f; } v; v.u = ((unsigned)h) << 16; return v.f;
}

__device__ inline void gl2lds16(const ushort* g, ushort* l) {
  __builtin_amdgcn_global_load_lds((const __attribute__((address_space(1))) void*)g,
                                   (__attribute__((address_space(3))) void*)l, 16, 0, 0);
}

// ---------------------------------------------------------------------------
// prep: downsample + split fp32 -> (hi,lo) bf16 K-major cat operands, AND
// s2[p] = sum_c b_ds[c,p]^2 (f,b are L2-resident at 8.4 MB - coalescing is moot)
__global__ __launch_bounds__(256) void k_prep(const float* __restrict__ f,
                                              const float* __restrict__ b,
                                              ushort* __restrict__ fcat,
                                              ushort* __restrict__ bcat,
                                              float* __restrict__ s2) {
  int idx = blockIdx.x * 256 + threadIdx.x;   // 524288
  int c = idx & 127, pos = idx >> 7;
  int x = pos & 63, y = pos >> 6;
  int src = c * 16384 + y * 256 + x * 2;
  float fv = f[src], bv = b[src];
  ushort fh = f2bf(fv); ushort fl = f2bf(fv - bf2f(fh));
  ushort bh = f2bf(bv); ushort bl = f2bf(bv - bf2f(bh));
  size_t base = (size_t)pos * 384;
  fcat[base + c] = fh; fcat[base + 128 + c] = fl; fcat[base + 256 + c] = fh;
  bcat[base + c] = bh; bcat[base + 128 + c] = bh; bcat[base + 256 + c] = bl;
  float sq = bv * bv;
#pragma unroll
  for (int off = 32; off; off >>= 1) sq += __shfl_down(sq, off);
  __shared__ float wsum[4];
  if ((threadIdx.x & 63) == 0) wsum[threadIdx.x >> 6] = sq;
  __syncthreads();
  if (threadIdx.x == 0) s2[blockIdx.x * 2]     = wsum[0] + wsum[1];
  if (threadIdx.x == 1) s2[blockIdx.x * 2 + 1] = wsum[2] + wsum[3];
}

// merged: blocks 0..15 -> mmp[a] (mask gate at p=pi(a)); 16..31 -> rnrm[p]
__global__ __launch_bounds__(256) void k_mmpnorm(const float* __restrict__ mask,
                                                 const float* __restrict__ s2,
                                                 float* __restrict__ mmp,
                                                 float* __restrict__ rnrm) {
  int bx = blockIdx.x, t = threadIdx.x;
  if (bx < 16) {
    int a = bx * 256 + t;
    int yb = a & 63, xb = a >> 6;               // p = pi(a)
    float s = 0.f;
    for (int dy = -1; dy <= 1; ++dy)
      for (int dx = -1; dx <= 1; ++dx) {
        int y = yb + dy, x = xb + dx;
        if ((unsigned)y < 64u && (unsigned)x < 64u)
          s += mask[y * 256 + x * 2];
      }
    mmp[a] = (s == 0.0f) ? 1.0f : 0.0f;
  } else {
    int p = (bx - 16) * 256 + t;
    int xb = p & 63, yb = p >> 6;
    float s = 0.f;
    for (int dy = -1; dy <= 1; ++dy)
      for (int dx = -1; dx <= 1; ++dx) {
        int y = yb + dy, x = xb + dx;
        if ((unsigned)y < 64u && (unsigned)x < 64u) s += s2[y * 64 + x];
      }
    rnrm[p] = rsqrtf(s + 1152.0f * 1.0e-4f);
  }
}

// ---------------------------------------------------------------------------
// MFMA bf16 GEMM, 128x128 tile, 4 waves, BK=64, global_load_lds + global XOR swizzle.
__global__ __launch_bounds__(256) void k_mfma_gemm(const ushort* __restrict__ A,
                                                   const ushort* __restrict__ B,
                                                   float* __restrict__ Out,
                                                   int Kdim, int lda, int ldb, int ldo) {
  __shared__ ushort As[128 * 64];
  __shared__ ushort Bs[128 * 64];
  int tid = threadIdx.x;
  int wave = tid >> 6, lane = tid & 63;
  int quad = lane >> 4, l16 = lane & 15;
  int m0 = blockIdx.y * 128, n0 = blockIdx.x * 128;
  int wm = (wave >> 1) * 64, wn = (wave & 1) * 64;
  int srow = lane >> 3;
  int g = lane & 7;
  int gperm = (g ^ srow) * 8;

  f4a16 acc[4][4];
#pragma unroll
  for (int i = 0; i < 4; ++i)
#pragma unroll
    for (int j = 0; j < 4; ++j) acc[i][j] = (f4a16){0.f, 0.f, 0.f, 0.f};

  for (int k0 = 0; k0 < Kdim; k0 += 64) {
#pragma unroll
    for (int i = 0; i < 4; ++i) {
      int rbase = wave * 32 + i * 8;
      gl2lds16(A + (size_t)(m0 + rbase + srow) * lda + k0 + gperm, &As[rbase * 64]);
      gl2lds16(B + (size_t)(n0 + rbase + srow) * ldb + k0 + gperm, &Bs[rbase * 64]);
    }
    __syncthreads();
#pragma unroll
    for (int s = 0; s < 2; ++s) {
      short8 afrag[4], bfrag[4];
#pragma unroll
      for (int t = 0; t < 4; ++t) {
        int am = wm + t * 16 + l16;
        int ga = ((s * 4 + quad) ^ (am & 7)) * 8;
        afrag[t] = *reinterpret_cast<const short8*>(&As[am * 64 + ga]);
        int bn = wn + t * 16 + l16;
        int gb = ((s * 4 + quad) ^ (bn & 7)) * 8;
        bfrag[t] = *reinterpret_cast<const short8*>(&Bs[bn * 64 + gb]);
      }
#pragma unroll
      for (int i = 0; i < 4; ++i)
#pragma unroll
        for (int j = 0; j < 4; ++j)
          acc[i][j] = __builtin_amdgcn_mfma_f32_16x16x32_bf16(afrag[i], bfrag[j], acc[i][j], 0, 0, 0);
    }
    __syncthreads();
  }
#pragma unroll
  for (int i = 0; i < 4; ++i)
#pragma unroll
    for (int j = 0; j < 4; ++j)
#pragma unroll
      for (int r = 0; r < 4; ++r)
        Out[(size_t)(m0 + wm + i * 16 + quad * 4 + r) * ldo + (n0 + wn + j * 16 + l16)] = acc[i][j][r];
}

// ---------------------------------------------------------------------------
// S0[p,q] = (sum of 9 diag-shifted D taps) * rnrm[p]
__global__ __launch_bounds__(256) void k_s0(const float* __restrict__ D,
                                            const float* __restrict__ rnrm,
                                            float* __restrict__ S0) {
  int p = blockIdx.x;
  int yb = p >> 6, xb = p & 63;
  float rp = rnrm[p];
  int t = threadIdx.x;
#pragma unroll
  for (int it = 0; it < 4; ++it) {
    int q = (it * 256 + t) << 2;
    int qy = q >> 6, qx = q & 63;
    f4a16 acc = (f4a16){0.f, 0.f, 0.f, 0.f};
#pragma unroll
    for (int dy = -1; dy <= 1; ++dy) {
      if ((unsigned)(yb + dy) >= 64u) continue;
      if ((unsigned)(qy + dy) >= 64u) continue;
#pragma unroll
      for (int dx = -1; dx <= 1; ++dx) {
        if ((unsigned)(xb + dx) >= 64u) continue;
        int delta = dy * 64 + dx;
        const float* base = D + (size_t)(p + delta) * 4096;
        f4u v;
        if (dx == -1 && qx == 0) {
          f4u r = *(const f4u*)(base + q + delta + 1);  // avoid negative addr
          v = (f4u){0.f, r.x, r.y, r.z};
        } else {
          v = *(const f4u*)(base + q + delta);
          if (dx == 1 && qx == 60) v.w = 0.f;
        }
        acc += v;
      }
    }
    acc *= rp;
    *(f4a16*)(S0 + ((size_t)p << 12) + q) = acc;
  }
}

// fuse1: F1[i,j] = sum_d S0[i+d, j+d], written permuted: Yp[pi(i)][b]=F1[i][pi(b)]
// second loop: float4 stores (LDS gather verified 2-way-bank-free)
__global__ __launch_bounds__(256) void k_fuse1(const float* __restrict__ S0,
                                               float* __restrict__ Yp) {
  __shared__ float row[4160];
  int i = blockIdx.x;
  int t = threadIdx.x;
  const float* r0 = S0 + (size_t)(i - 1) * 4096;
  const float* r1 = S0 + (size_t)i * 4096;
  const float* r2 = S0 + (size_t)(i + 1) * 4096;
  bool up = (i > 0), dn = (i < 4095);
#pragma unroll
  for (int jj = 0; jj < 4; ++jj) {
    int j = (jj * 256 + t) << 2;
    f4u s = *(const f4u*)(r1 + j);
    if (up) {
      f4u a;
      if (j == 0) { f4u r = *(const f4u*)r0; a = (f4u){0.f, r.x, r.y, r.z}; }
      else a = *(const f4u*)(r0 + j - 1);
      s += a;
    }
    if (dn) {
      f4u d = *(const f4u*)(r2 + j + 1);
      if (j == 4092) d.w = 0.f;
      s += d;
    }
    int base = j + (j >> 6);
    row[base + 0] = s.x; row[base + 1] = s.y; row[base + 2] = s.z; row[base + 3] = s.w;
  }
  __syncthreads();
  int a = ((i & 63) << 6) | (i >> 6);
  float* orow = Yp + ((size_t)a << 12);
#pragma unroll
  for (int bb = 0; bb < 4; ++bb) {
    int b4 = (bb * 256 + t) << 2;
    f4a16 o;
#pragma unroll
    for (int k = 0; k < 4; ++k) {
      int jT = (((b4 + k) & 63) << 6) | ((b4 + k) >> 6);
      o[k] = row[jT + (jT >> 6)];
    }
    *(f4a16*)(orow + b4) = o;
  }
}

// softmax partials over u of logits x = 10 * mmp[u] * diag3(Yp)[u,v]
__global__ __launch_bounds__(256) void k_smax_part(const float* __restrict__ Yp,
                                                   const float* __restrict__ mmp,
                                                   float* __restrict__ pm,
                                                   float* __restrict__ ps) {
  int v = (blockIdx.x * 256 + threadIdx.x) << 2;
  int chunk = blockIdx.y;
  f4a16 m = (f4a16){-1e30f, -1e30f, -1e30f, -1e30f};
  f4a16 s = (f4a16){0.f, 0.f, 0.f, 0.f};
  int u0 = chunk * (4096 / NCHUNK);
  for (int u = u0; u < u0 + (4096 / NCHUNK); ++u) {
    const float* row = Yp + ((size_t)u << 12);
    f4u tv = *(const f4u*)(row + v);
    if (u > 0) {
      f4u a;
      if (v == 0) { f4u r = *(const f4u*)(row - 4096); a = (f4u){0.f, r.x, r.y, r.z}; }
      else a = *(const f4u*)(row - 4096 + v - 1);
      tv += a;
    }
    if (u < 4095) {
      f4u d = *(const f4u*)(row + 4096 + v + 1);
      if (v == 4092) d.w = 0.f;
      tv += d;
    }
    float g = 10.0f * mmp[u];
    f4u x = tv * g;
#pragma unroll
    for (int l = 0; l < 4; ++l) {
      float xl = x[l];
      if (xl > m[l]) { s[l] = s[l] * __expf(m[l] - xl) + 1.0f; m[l] = xl; }
      else           { s[l] += __expf(xl - m[l]); }
    }
  }
  *(f4a16*)(pm + chunk * NP + v) = m;
  *(f4a16*)(ps + chunk * NP + v) = s;
}

// ---------------------------------------------------------------------------
// epilogue (flattened 6144-block grid):
//   gx < 4096: attnT tile (a0,b0) with LOCAL softmax reduction over pm/ps,
//              AT[q=pi(b)][a] = bf16(mmp[a]*exp(x-mcol)*rscol), uint4 stores.
//   gx >= 4096: VtT'[k2][a] = bf16(Vt[k2][pi(a)]) (LDS 64x64 transpose).
__global__ __launch_bounds__(256) void k_epilogue(const float* __restrict__ Yp,
                                                  const float* __restrict__ pm,
                                                  const float* __restrict__ ps,
                                                  const float* __restrict__ mmp,
                                                  ushort* __restrict__ AT,
                                                  const float* __restrict__ bimg,
                                                  ushort* __restrict__ VtT) {
  __shared__ float T[64][65];
  __shared__ float pmS[4][64];
  __shared__ float psS[4][64];
  __shared__ float mS[64];
  __shared__ float rsS[64];
  int gx = blockIdx.x;
  int t = threadIdx.x;
  if (gx < 4096) {
    int a0 = (gx & 63) * 64, b0 = (gx >> 6) * 64;
    // local reduction for columns b0..b0+63 (4 thread-groups x 16 chunks)
    int j = t & 63, grp = t >> 6;
    float m = -1e30f, s = 0.f;
    for (int ch = grp * 16; ch < grp * 16 + 16; ++ch) {
      float m2 = pm[ch * NP + b0 + j], s2 = ps[ch * NP + b0 + j];
      if (m2 > m) { s = s * __expf(m - m2) + s2; m = m2; }
      else        { s += s2 * __expf(m2 - m); }
    }
    pmS[grp][j] = m; psS[grp][j] = s;
    __syncthreads();
    if (grp == 0) {
      for (int g2 = 1; g2 < 4; ++g2) {
        float m2 = pmS[g2][j], s2 = psS[g2][j];
        if (m2 > m) { s = s * __expf(m - m2) + s2; m = m2; }
        else        { s += s2 * __expf(m2 - m); }
      }
      mS[j] = m; rsS[j] = 1.0f / s;
    }
    __syncthreads();
    // attn tile compute
    int i = t >> 4, j4 = (t & 15) << 2;
    f4a16 mc = *(const f4a16*)&mS[j4];
    f4a16 rs = *(const f4a16*)&rsS[j4];
#pragma unroll
    for (int r = 0; r < 4; ++r) {
      int al = r * 16 + i;
      int a = a0 + al;
      const float* row = Yp + ((size_t)a << 12);
      int b = b0 + j4;
      f4u y = *(const f4u*)(row + b);
      if (a > 0) {
        f4u u_;
        if (b == 0) { f4u rr = *(const f4u*)(row - 4096); u_ = (f4u){0.f, rr.x, rr.y, rr.z}; }
        else u_ = *(const f4u*)(row - 4096 + b - 1);
        y += u_;
      }
      if (a < 4095) {
        f4u d = *(const f4u*)(row + 4096 + b + 1);
        if (b == 4092) d.w = 0.f;
        y += d;
      }
      float g = mmp[a];
      f4u x = y * (10.0f * g);
#pragma unroll
      for (int l = 0; l < 4; ++l)
        T[al][j4 + l] = g * __expf(x[l] - mc[l]) * rs[l];
    }
    __syncthreads();
    // transposed write, 8 packed bf16 (16B) per store
    int by0 = b0 >> 6;
    int cgrp = (t & 7) * 8;
#pragma unroll
    for (int pass = 0; pass < 2; ++pass) {
      int bl = pass * 32 + (t >> 3);
      int q = bl * 64 + by0;                   // pi(b0 + bl)
      uint4 w;
      w.x = (unsigned)f2bf(T[cgrp + 0][bl]) | ((unsigned)f2bf(T[cgrp + 1][bl]) << 16);
      w.y = (unsigned)f2bf(T[cgrp + 2][bl]) | ((unsigned)f2bf(T[cgrp + 3][bl]) << 16);
      w.z = (unsigned)f2bf(T[cgrp + 4][bl]) | ((unsigned)f2bf(T[cgrp + 5][bl]) << 16);
      w.w = (unsigned)f2bf(T[cgrp + 6][bl]) | ((unsigned)f2bf(T[cgrp + 7][bl]) << 16);
      *(uint4*)(AT + ((size_t)q << 12) + a0 + cgrp) = w;
    }
  } else {
    int k2 = gx - 4096;
    int c = k2 >> 4, dy = (k2 >> 2) & 3, dx = k2 & 3;
    int px = t & 63;
#pragma unroll
    for (int r = 0; r < 16; ++r) {
      int py = r * 4 + (t >> 6);
      int sy = 2 * py + dy - 1, sx = 2 * px + dx - 1;
      float v = 0.f;
      if ((unsigned)sy < (unsigned)HF && (unsigned)sx < (unsigned)WF)
        v = bimg[c * 16384 + sy * 128 + sx];
      T[py][px] = v;
    }
    __syncthreads();
    ushort* orow = VtT + (size_t)k2 * 4096;
#pragma unroll
    for (int r = 0; r < 16; ++r) {
      int a = r * 256 + t;
      orow[a] = f2bf(T[a & 63][a >> 6]);
    }
  }
}

// scatter M[(c,dy,dx), q] -> out (transposed conv, lhs_dilation=2), /4
__global__ __launch_bounds__(256) void k_scatter(const float* __restrict__ M,
                                                 float* __restrict__ out) {
  int idx = blockIdx.x * 256 + threadIdx.x;
  int ox = idx & 127, oy = (idx >> 7) & 127, c = idx >> 14;
  int qy[2], dyv[2], qx[2], dxv[2];
  if (oy & 1) { qy[0] = (oy - 1) >> 1; dyv[0] = 2; qy[1] = (oy + 1) >> 1; dyv[1] = 0; }
  else        { qy[0] = (oy >> 1) - 1; dyv[0] = 3; qy[1] = oy >> 1;       dyv[1] = 1; }
  if (ox & 1) { qx[0] = (ox - 1) >> 1; dxv[0] = 2; qx[1] = (ox + 1) >> 1; dxv[1] = 0; }
  else        { qx[0] = (ox >> 1) - 1; dxv[0] = 3; qx[1] = ox >> 1;       dxv[1] = 1; }
  float s = 0.f;
#pragma unroll
  for (int i = 0; i < 2; ++i) {
    if ((unsigned)qy[i] >= 64u) continue;
#pragma unroll
    for (int j = 0; j < 2; ++j) {
      if ((unsigned)qx[j] >= 64u) continue;
      int k = c * 16 + dyv[i] * 4 + dxv[j];
      s += M[(size_t)k * NP + qy[i] * 64 + qx[j]];
    }
  }
  out[idx] = 0.25f * s;
}

// ---------------------------------------------------------------------------
extern "C" void kernel_launch(void* const* d_in, const int* in_sizes, int n_in,
                              void* d_out, int out_size, void* d_ws, size_t ws_size,
                              hipStream_t stream) {
  const float* f_all = (const float*)d_in[0];
  const float* b_all = (const float*)d_in[1];
  const float* m_all = (const float*)d_in[2];
  float* out = (float*)d_out;

  float* ws = (float*)d_ws;
  float* bufD = ws;                          // 64MB: D -> Yp -> M
  float* bufS = ws + 16777216;               // 64MB: {fcat,bcat} -> S0 -> {AT, VtT}
  ushort* fcat = (ushort*)bufS;
  ushort* bcat = (ushort*)(bufS + 786432);
  float* S0  = bufS;
  float* Yp  = bufD;
  ushort* AT  = (ushort*)bufS;               // 32MB
  ushort* VtT = (ushort*)(bufS + 8388608);   // 16MB
  float* Mbuf = bufD;                        // 32MB (clobbers Yp)
  float* smalls = ws + 2 * 16777216;
  float* s2    = smalls;
  float* rnrm  = s2 + 4096;
  float* mmp   = rnrm + 4096;
  float* pm    = mmp + 4096;
  float* ps    = pm + NCHUNK * NP;

  const size_t zsF = (size_t)CDIM * HF * WF;
  const size_t zsM = (size_t)HF * WF;

  for (int it = 0; it < 2; ++it) {
    const float* f = f_all + it * zsF;
    const float* b = b_all + it * zsF;
    const float* mk = m_all + it * zsM;
    float* o = out + it * zsF;

    k_prep<<<2048, 256, 0, stream>>>(f, b, fcat, bcat, s2);
    k_mmpnorm<<<32, 256, 0, stream>>>(mk, s2, mmp, rnrm);
    // D[p,q] (fp32-accurate via split-bf16, K=384)
    k_mfma_gemm<<<dim3(32, 32), 256, 0, stream>>>(bcat, fcat, bufD, 384, 384, 384, NP);
    k_s0<<<4096, 256, 0, stream>>>(bufD, rnrm, S0);
    k_fuse1<<<4096, 256, 0, stream>>>(S0, Yp);
    k_smax_part<<<dim3(4, NCHUNK), 256, 0, stream>>>(Yp, mmp, pm, ps);
    k_epilogue<<<6144, 256, 0, stream>>>(Yp, pm, ps, mmp, AT, b, VtT);
    // M[k2,q] = sum_a VtT[k2,a] * AT[q,a]   (K=4096)
    k_mfma_gemm<<<dim3(32, 16), 256, 0, stream>>>(VtT, AT, Mbuf, NP, NP, NP, NP);
    k_scatter<<<8192, 256, 0, stream>>>(Mbuf, o);
  }
}